// Round 3
// baseline (103.684 us; speedup 1.0000x reference)
//
#include <hip/hip_runtime.h>

// NonMaximaSuppression2d: x shape (B=8, C=128, H=256, W=256) fp32.
// out[p] = x[p] if x[p] > max(0, 8 replicate-padded 3x3 neighbors) else 0.
//
// Separable + shuffle version: each wave owns a full 256-wide row (64 lanes
// x float4). Per output row each thread does exactly ONE dwordx4 load; the
// left/right halo columns come from neighbor lanes via __shfl of the
// per-column 3-row maxes. Replicate padding:
//  - rows: clamped row index (top/bottom tap aliases the row itself)
//  - cols: edge lanes use their own boundary column-max (which INCLUDES the
//    center tap) — exactly the reference semantics, where w=0/w=255 pixels
//    see themselves as their replicated left/right neighbor.

#define NMS_W 256
#define NMS_H 256
#define ROWS 16

__global__ __launch_bounds__(256) void nms2d_kernel(
    const float* __restrict__ x, float* __restrict__ out) {
    const int lane = threadIdx.x & 63;        // float4-segment along W
    const int wid  = threadIdx.x >> 6;        // wave id in block: 0..3
    const int gid  = blockIdx.x;
    const int blocksPerPlane = (NMS_H / ROWS) / 4;   // 4
    const long plane = gid / blocksPerPlane;         // b*C + c
    const int  chunk = gid % blocksPerPlane;
    const int  row0  = (chunk * 4 + wid) * ROWS;

    const float* p = x   + plane * (long)(NMS_H * NMS_W);
    float*       q = out + plane * (long)(NMS_H * NMS_W);
    const int c0 = lane * 4;

    // Rolling 3-row window in registers (one float4 per row).
    float4 t = *reinterpret_cast<const float4*>(
        p + (long)(row0 == 0 ? 0 : row0 - 1) * NMS_W + c0);
    float4 m = *reinterpret_cast<const float4*>(p + (long)row0 * NMS_W + c0);

#pragma unroll
    for (int r = 0; r < ROWS; ++r) {
        int rb = row0 + r + 1;
        if (rb > NMS_H - 1) rb = NMS_H - 1;   // bottom replicate
        const float4 b = *reinterpret_cast<const float4*>(
            p + (long)rb * NMS_W + c0);

        // Full column maxes (include center row) and center-excluded ones.
        const float cm0 = fmaxf(fmaxf(t.x, m.x), b.x);
        const float cm1 = fmaxf(fmaxf(t.y, m.y), b.y);
        const float cm2 = fmaxf(fmaxf(t.z, m.z), b.z);
        const float cm3 = fmaxf(fmaxf(t.w, m.w), b.w);
        const float tb0 = fmaxf(t.x, b.x);
        const float tb1 = fmaxf(t.y, b.y);
        const float tb2 = fmaxf(t.z, b.z);
        const float tb3 = fmaxf(t.w, b.w);

        // Halo column maxes from neighbor lanes.
        float left  = __shfl_up(cm3, 1);
        float right = __shfl_down(cm0, 1);
        // Replicate padding at row ends: the out-of-row neighbor column is
        // the boundary column itself (center included -> edge suppressed).
        if (lane == 0)  left  = cm0;
        if (lane == 63) right = cm3;

        // Neighborhood max (8 neighbors + implicit 0 channel).
        const float n0 = fmaxf(fmaxf(fmaxf(left, tb0), cm1), 0.0f);
        const float n1 = fmaxf(fmaxf(fmaxf(cm0,  tb1), cm2), 0.0f);
        const float n2 = fmaxf(fmaxf(fmaxf(cm1,  tb2), cm3), 0.0f);
        const float n3 = fmaxf(fmaxf(fmaxf(cm2,  tb3), right), 0.0f);

        float4 o;
        o.x = (m.x > n0) ? m.x : 0.0f;
        o.y = (m.y > n1) ? m.y : 0.0f;
        o.z = (m.z > n2) ? m.z : 0.0f;
        o.w = (m.w > n3) ? m.w : 0.0f;
        *reinterpret_cast<float4*>(q + (long)(row0 + r) * NMS_W + c0) = o;

        t = m; m = b;
    }
}

extern "C" void kernel_launch(void* const* d_in, const int* in_sizes, int n_in,
                              void* d_out, int out_size, void* d_ws, size_t ws_size,
                              hipStream_t stream) {
    const float* x = (const float*)d_in[0];
    float* out = (float*)d_out;
    const int planes = out_size / (NMS_H * NMS_W);           // 1024
    const int grid = planes * ((NMS_H / ROWS) / 4);          // 4096 blocks
    nms2d_kernel<<<grid, 256, 0, stream>>>(x, out);
}

// Round 5
// 86.683 us; speedup vs baseline: 1.1961x; 1.1961x over previous
//
#include <hip/hip_runtime.h>

// NonMaximaSuppression2d: x shape (B=8, C=128, H=256, W=256) fp32.
// out[p] = x[p] if x[p] > max(0, 8 replicate-padded 3x3 neighbors) else 0.
// Reference's running max starts at 0 (center conv channel is all-zero),
// so negative x is always suppressed.
//
// R5 = R2 structure (scalar edge taps — L1 hits, NO cross-lane shuffles;
// R3 showed ds_bpermute in the inner loop regresses) + ROWS 16 (halved
// vertical halo re-fetch) + nontemporal stores (output is write-once;
// keep it from evicting halo rows in L2). Uses clang ext_vector_type
// (native vector) because __builtin_nontemporal_store rejects
// HIP_vector_type structs.

#define NMS_W 256
#define NMS_H 256
#define ROWS 16

typedef float f32x4 __attribute__((ext_vector_type(4)));

__global__ __launch_bounds__(256) void nms2d_kernel(
    const float* __restrict__ x, float* __restrict__ out) {
    const int lane = threadIdx.x & 63;        // float4-segment along W
    const int wid  = threadIdx.x >> 6;        // wave id in block: 0..3
    const int gid  = blockIdx.x;
    const int blocksPerPlane = (NMS_H / ROWS) / 4;   // 4
    const long plane = gid / blocksPerPlane;         // b*C + c
    const int  chunk = gid % blocksPerPlane;
    const int  row0  = (chunk * 4 + wid) * ROWS;

    const float* p = x   + plane * (long)(NMS_H * NMS_W);
    float*       q = out + plane * (long)(NMS_H * NMS_W);

    const int c0 = lane * 4;
    // Replicate padding via clamped column indices.
    const int cl = (c0 == 0) ? 0 : c0 - 1;
    const int cr = (c0 == NMS_W - 4) ? NMS_W - 1 : c0 + 4;

    float t[6], m[6], b[6];
    auto load6 = [&](int r, float* a) {
        const float* rp = p + (long)r * NMS_W;
        const f32x4 v = *reinterpret_cast<const f32x4*>(rp + c0);
        a[0] = rp[cl]; a[1] = v.x; a[2] = v.y; a[3] = v.z; a[4] = v.w; a[5] = rp[cr];
    };

    // Replicate padding on top edge: row -1 aliases row 0.
    load6(row0 == 0 ? 0 : row0 - 1, t);
    load6(row0, m);

#pragma unroll
    for (int r = 0; r < ROWS; ++r) {
        int rb = row0 + r + 1;
        if (rb > NMS_H - 1) rb = NMS_H - 1;   // bottom replicate
        load6(rb, b);

        f32x4 o;
#pragma unroll
        for (int k = 0; k < 4; ++k) {
            // max over 8 non-center neighbors and the implicit 0 channel
            float mx = fmaxf(fmaxf(t[k], t[k + 1]), t[k + 2]);       // top 3
            mx = fmaxf(mx, fmaxf(m[k], m[k + 2]));                   // mid, skip center
            mx = fmaxf(mx, fmaxf(fmaxf(b[k], b[k + 1]), b[k + 2]));  // bottom 3
            mx = fmaxf(mx, 0.0f);
            const float c = m[k + 1];
            o[k] = (c > mx) ? c : 0.0f;
        }
        __builtin_nontemporal_store(
            o, reinterpret_cast<f32x4*>(q + (long)(row0 + r) * NMS_W + c0));

#pragma unroll
        for (int k = 0; k < 6; ++k) { t[k] = m[k]; m[k] = b[k]; }
    }
}

extern "C" void kernel_launch(void* const* d_in, const int* in_sizes, int n_in,
                              void* d_out, int out_size, void* d_ws, size_t ws_size,
                              hipStream_t stream) {
    const float* x = (const float*)d_in[0];
    float* out = (float*)d_out;
    const int planes = out_size / (NMS_H * NMS_W);           // 1024
    const int grid = planes * ((NMS_H / ROWS) / 4);          // 4096 blocks
    nms2d_kernel<<<grid, 256, 0, stream>>>(x, out);
}